// Round 4
// baseline (131.986 us; speedup 1.0000x reference)
//
#include <hip/hip_runtime.h>

#define A_N   256
#define T_TOK 32
#define B_N   256
#define V_FRM 16
#define D_DIM 512
#define K_LOG2E 144.269504089f   // TAU * log2(e), TAU = 100

typedef _Float16 half8 __attribute__((ext_vector_type(8)));
typedef _Float16 half4v __attribute__((ext_vector_type(4)));
typedef float    floatx4 __attribute__((ext_vector_type(4)));

__device__ __forceinline__ float fast_exp2(float x) {
#if __has_builtin(__builtin_amdgcn_exp2f)
  return __builtin_amdgcn_exp2f(x);
#else
  return exp2f(x);
#endif
}
__device__ __forceinline__ float fast_rcp(float x) {
#if __has_builtin(__builtin_amdgcn_rcpf)
  return __builtin_amdgcn_rcpf(x);
#else
  return 1.0f / x;
#endif
}

// async global->LDS, 16B/lane. LDS dest = wave-uniform base + lane*16.
__device__ __forceinline__ void async_copy16(const void* g, void* l) {
#if __has_builtin(__builtin_amdgcn_global_load_lds)
  __builtin_amdgcn_global_load_lds((const __attribute__((address_space(1))) void*)g,
                                   (__attribute__((address_space(3))) void*)l, 16, 0, 0);
#else
  const int lane = threadIdx.x & 63;
  *(float4*)((char*)l + lane * 16) = *(const float4*)g;
#endif
}

// ---------------- Kernel 1: L2-normalize rows + cast to fp16 ----------------
// 16-lane group per row, 16 rows per block. (R3 version — measured win)
__global__ __launch_bounds__(256) void norm_cast_kernel(
    const float* __restrict__ text, const float* __restrict__ video,
    _Float16* __restrict__ H)
{
  const int g   = threadIdx.x >> 4;
  const int l   = threadIdx.x & 15;
  const int rid = blockIdx.x * 16 + g;   // 0..12287
  const float* src = (rid < A_N * T_TOK)
                       ? (text + (size_t)rid * D_DIM)
                       : (video + (size_t)(rid - A_N * T_TOK) * D_DIM);
  float4 c[8];
#pragma unroll
  for (int k = 0; k < 8; ++k) c[k] = *(const float4*)(src + k * 64 + l * 4);
  float s0 = 0.f, s1 = 0.f;
#pragma unroll
  for (int k = 0; k < 8; k += 2) {
    s0 += c[k].x * c[k].x + c[k].y * c[k].y + c[k].z * c[k].z + c[k].w * c[k].w;
    s1 += c[k+1].x * c[k+1].x + c[k+1].y * c[k+1].y + c[k+1].z * c[k+1].z + c[k+1].w * c[k+1].w;
  }
  float ss = s0 + s1;
#pragma unroll
  for (int d = 1; d < 16; d <<= 1) ss += __shfl_xor(ss, d);
  const float s = 1.0f / fmaxf(sqrtf(ss), 1e-6f);
  _Float16* dst = H + (size_t)rid * D_DIM;
#pragma unroll
  for (int k = 0; k < 8; ++k) {
    half4v h;
    h[0] = (_Float16)(c[k].x * s); h[1] = (_Float16)(c[k].y * s);
    h[2] = (_Float16)(c[k].z * s); h[3] = (_Float16)(c[k].w * s);
    *(half4v*)(dst + k * 64 + l * 4) = h;
  }
}

// ---------------- Kernel 2: fused GEMM + dual softmax pooling ----------------
// R2 version (measured 64.4 us): block tile 128x128, 4 waves 2x2, 64x64/wave.
// Epilogue: single-round LDS transpose buffer X[8][32 t][20], serial softmaxes.
// R3 lesson: 2-round batching (37.9KB LDS, 80 VGPR) dropped occupancy 36->30%
// and slowed everything uniformly — keep LDS at 21.5KB / VGPR ~60.
__global__ __launch_bounds__(256, 2) void score_kernel(
    const _Float16* __restrict__ H, const float* __restrict__ tmask,
    float* __restrict__ out)
{
  __shared__ __align__(16) char smem[21120];
  _Float16* sA = (_Float16*)smem;
  _Float16* sB = (_Float16*)(smem + 8192);
  float*    X  = (float*)smem;            // pair stride 644 floats
  float*    LM = (float*)(smem + 20608);  // [128]

  const int tid  = threadIdx.x;
  const int w    = tid >> 6;
  const int lane = tid & 63;
  const int bn   = blockIdx.x;       // 0..31 -> 8 b's
  const int bm   = blockIdx.y;       // 0..63 -> 4 a's
  const int mBase = bm * 128;
  const int nBase = bn * 128;

  if (tid < 128) LM[tid] = tmask[mBase + tid];

  const char* gA = (const char*)(H + (size_t)mBase * D_DIM);
  const char* gB = (const char*)(H + (size_t)(A_N * T_TOK + nBase) * D_DIM);
  const int rowoff = (lane >> 2) * 1024 + (lane & 3) * 16;

  floatx4 acc[4][4];
#pragma unroll
  for (int i = 0; i < 4; ++i)
#pragma unroll
    for (int j = 0; j < 4; ++j) acc[i][j] = {0.f, 0.f, 0.f, 0.f};

  const int colL = lane & 15;
  const int quad = lane >> 4;
  const int aRowBase = (w >> 1) * 64;
  const int bRowBase = (w & 1) * 64;

  for (int kt = 0; kt < 16; ++kt) {
    const int kb = kt * 64;
#pragma unroll
    for (int is = 0; is < 2; ++is) {
      const int rbase = w * 32 + is * 16;
      async_copy16(gA + (size_t)rbase * 1024 + rowoff + kb, (char*)sA + rbase * 64);
      async_copy16(gB + (size_t)rbase * 1024 + rowoff + kb, (char*)sB + rbase * 64);
    }
    __syncthreads();

    half8 aF[4], bF[4];
#pragma unroll
    for (int i = 0; i < 4; ++i)
      aF[i] = *(const half8*)&sA[(aRowBase + i * 16 + colL) * 32 + quad * 8];
#pragma unroll
    for (int j = 0; j < 4; ++j)
      bF[j] = *(const half8*)&sB[(bRowBase + j * 16 + colL) * 32 + quad * 8];
#pragma unroll
    for (int i = 0; i < 4; ++i)
#pragma unroll
      for (int j = 0; j < 4; ++j)
        acc[i][j] = __builtin_amdgcn_mfma_f32_16x16x32_f16(aF[i], bF[j], acc[i][j], 0, 0, 0);
    __syncthreads();
  }

  // ---- fold text mask into accumulators (masked logits become exact 0) ----
#pragma unroll
  for (int ip = 0; ip < 2; ++ip)
#pragma unroll
    for (int ih = 0; ih < 2; ++ih)
#pragma unroll
      for (int rr = 0; rr < 4; ++rr) {
        const float m = LM[(w >> 1) * 64 + (ip * 2 + ih) * 16 + quad * 4 + rr];
#pragma unroll
        for (int j = 0; j < 4; ++j) acc[ip * 2 + ih][j][rr] *= m;
      }

  // ---- epilogue: 4 rounds of 8 pairs (j = round; pair p = w*2+ip) ----
  const int pG = tid >> 5;          // pair this thread processes (phases A/B)
  const int tA = tid & 31;          // t row (phase A)
  const int vB = (tid >> 1) & 15;   // v column (phase B)
  const int hB = tid & 1;           // t half (phase B)

  for (int rj = 0; rj < 4; ++rj) {
    // write 2 pairs per wave into X[p][t][v]  (t stride 20, pair stride 644)
#pragma unroll
    for (int ip = 0; ip < 2; ++ip) {
      float* basep = X + (w * 2 + ip) * 644 + (quad * 4) * 20 + colL;
#pragma unroll
      for (int ih = 0; ih < 2; ++ih)
#pragma unroll
        for (int rr = 0; rr < 4; ++rr)
          basep[(ih * 16 + rr) * 20] = acc[ip * 2 + ih][rj][rr];
    }
    __syncthreads();

    // ---------- phase A: t2v (serial softmax over v per (pair,t) row) ----------
    const float* rowp = X + pG * 644 + tA * 20;
    float xv[16];
    *(float4*)(&xv[0])  = *(const float4*)(rowp);
    *(float4*)(&xv[4])  = *(const float4*)(rowp + 4);
    *(float4*)(&xv[8])  = *(const float4*)(rowp + 8);
    *(float4*)(&xv[12]) = *(const float4*)(rowp + 12);
    float t8[8];
#pragma unroll
    for (int i = 0; i < 8; ++i) t8[i] = fmaxf(xv[i], xv[i + 8]);
#pragma unroll
    for (int i = 0; i < 4; ++i) t8[i] = fmaxf(t8[i], t8[i + 4]);
    t8[0] = fmaxf(t8[0], t8[2]); t8[1] = fmaxf(t8[1], t8[3]);
    const float mA  = fmaxf(t8[0], t8[1]);
    const float mAK = mA * K_LOG2E;
    float se0 = 0.f, se1 = 0.f, sx0 = 0.f, sx1 = 0.f;
#pragma unroll
    for (int i = 0; i < 16; i += 2) {
      float e0 = fast_exp2(fmaf(xv[i],     K_LOG2E, -mAK));
      float e1 = fast_exp2(fmaf(xv[i + 1], K_LOG2E, -mAK));
      se0 += e0; se1 += e1;
      sx0 = fmaf(xv[i], e0, sx0); sx1 = fmaf(xv[i + 1], e1, sx1);
    }
    const float tv = (sx0 + sx1) * fast_rcp(se0 + se1);  // exact 0 for masked t

    // L2 t2v: masked softmax over 32 t (lanes of the 32-group)
    const float mv = (tv != 0.0f) ? tv : -1e30f;
    float m2 = mv;
#pragma unroll
    for (int d = 1; d < 32; d <<= 1) m2 = fmaxf(m2, __shfl_xor(m2, d));
    const float e2 = fast_exp2(fmaf(mv, K_LOG2E, -m2 * K_LOG2E));
    float s2 = e2, sx2 = mv * e2;    // masked: e2=+0, mv*e2=-0 -> no effect
#pragma unroll
    for (int d = 1; d < 32; d <<= 1) {
      s2 += __shfl_xor(s2, d);  sx2 += __shfl_xor(sx2, d);
    }
    const float t2v_ab = sx2 * fast_rcp(s2);

    // ---------- phase B: v2t (serial masked softmax over t per (pair,v)) ----------
    const float* colp = X + pG * 644 + hB * 320 + vB;
    float mm[16];
#pragma unroll
    for (int i = 0; i < 16; ++i) {
      const float xx = colp[i * 20];
      mm[i] = (xx != 0.0f) ? xx : -1e30f;
    }
    float u8[8];
#pragma unroll
    for (int i = 0; i < 8; ++i) u8[i] = fmaxf(mm[i], mm[i + 8]);
#pragma unroll
    for (int i = 0; i < 4; ++i) u8[i] = fmaxf(u8[i], u8[i + 4]);
    u8[0] = fmaxf(u8[0], u8[2]); u8[1] = fmaxf(u8[1], u8[3]);
    float mB = fmaxf(u8[0], u8[1]);
    mB = fmaxf(mB, __shfl_xor(mB, 1));         // combine the two t-halves
    const float mBK = mB * K_LOG2E;
    float sb0 = 0.f, sb1 = 0.f, xb0 = 0.f, xb1 = 0.f;
#pragma unroll
    for (int i = 0; i < 16; i += 2) {
      float e0 = fast_exp2(fmaf(mm[i],     K_LOG2E, -mBK));  // masked -> +0
      float e1 = fast_exp2(fmaf(mm[i + 1], K_LOG2E, -mBK));
      sb0 += e0; sb1 += e1;
      xb0 = fmaf(mm[i], e0, xb0); xb1 = fmaf(mm[i + 1], e1, xb1);
    }
    float seB = sb0 + sb1, sxB = xb0 + xb1;
    seB += __shfl_xor(seB, 1);  sxB += __shfl_xor(sxB, 1);
    const float v2t_v = sxB * fast_rcp(seB);

    // L2 v2t: softmax over 16 v (lane bits 1..4)
    float m3 = v2t_v;
#pragma unroll
    for (int d = 2; d < 32; d <<= 1) m3 = fmaxf(m3, __shfl_xor(m3, d));
    const float e3 = fast_exp2(fmaf(v2t_v, K_LOG2E, -m3 * K_LOG2E));
    float s3 = e3, sx3 = v2t_v * e3;
#pragma unroll
    for (int d = 2; d < 32; d <<= 1) {
      s3 += __shfl_xor(s3, d);  sx3 += __shfl_xor(sx3, d);
    }
    const float v2t_ab = sx3 * fast_rcp(s3);

    if ((tid & 31) == 0) {
      const int aL = (pG >> 2) * 2 + (pG & 1);
      const int bL = ((pG >> 1) & 1) * 4 + rj;
      out[(bm * 4 + aL) * B_N + bn * 8 + bL] = 0.5f * (t2v_ab + v2t_ab);
    }
    __syncthreads();   // protect X before next round's writes
  }
}

extern "C" void kernel_launch(void* const* d_in, const int* in_sizes, int n_in,
                              void* d_out, int out_size, void* d_ws, size_t ws_size,
                              hipStream_t stream) {
  const float* text  = (const float*)d_in[0];
  const float* video = (const float*)d_in[1];
  const float* tmask = (const float*)d_in[2];
  float* out = (float*)d_out;
  _Float16* H = (_Float16*)d_ws;

  norm_cast_kernel<<<(A_N * T_TOK + B_N * V_FRM) / 16, 256, 0, stream>>>(text, video, H);
  score_kernel<<<dim3(B_N * V_FRM / 128, A_N * T_TOK / 128), 256, 0, stream>>>(H, tmask, out);
}